// Round 1
// baseline (328.832 us; speedup 1.0000x reference)
//
#include <hip/hip_runtime.h>

// MultiHeadSelfAttention: B=4, N=2048, D=1024, H=16, Hd=64
// Strategy: bf16 MFMA (16x16x32) for QKV GEMM, flash attention, proj GEMM.
// fp32 accumulate everywhere; bias + 1/sqrt(Hd) fused into QKV epilogue.

typedef __attribute__((ext_vector_type(8))) short bf16x8;
typedef __attribute__((ext_vector_type(4))) short s16x4;
typedef __attribute__((ext_vector_type(4))) float f32x4;

__device__ static inline short f2bf(float f) {
  unsigned u = __builtin_bit_cast(unsigned, f);
  unsigned r = (u + 0x7fffu + ((u >> 16) & 1u)) >> 16;
  return (short)r;
}

__device__ static inline void gload_lds16(const void* g, void* l) {
  __builtin_amdgcn_global_load_lds(
      (const __attribute__((address_space(1))) void*)g,
      (__attribute__((address_space(3))) void*)l, 16, 0, 0);
}

__device__ static inline float rmax16(float v) {
  v = fmaxf(v, __shfl_xor(v, 1));
  v = fmaxf(v, __shfl_xor(v, 2));
  v = fmaxf(v, __shfl_xor(v, 4));
  v = fmaxf(v, __shfl_xor(v, 8));
  return v;
}
__device__ static inline float rsum16(float v) {
  v += __shfl_xor(v, 1);
  v += __shfl_xor(v, 2);
  v += __shfl_xor(v, 4);
  v += __shfl_xor(v, 8);
  return v;
}

// ---------------- fp32 -> bf16 convert ----------------
__global__ void cvt_f32_bf16(const float* __restrict__ in, short* __restrict__ out, int n4) {
  int i = blockIdx.x * 256 + threadIdx.x;
  if (i < n4) {
    float4 v = ((const float4*)in)[i];
    s16x4 o4 = { f2bf(v.x), f2bf(v.y), f2bf(v.z), f2bf(v.w) };
    ((s16x4*)out)[i] = o4;
  }
}

// ---------------- GEMM C = A[M,K] * B[N,K]^T (+bias) ----------------
// 128x128 tile, BK=32, 4 waves (2x2), each wave 64x64 = 4x4 MFMA frags.
// LDS linear, global-source XOR swizzle (chunk ^= row&3) -> 2-way reads.
// EPI=0: scatter q (pre-scaled 0.125), k as [B,H,N,Hd], v as [B,H,Hd,N] bf16.
// EPI=1: fp32 out + bias.
template <int EPI>
__global__ __launch_bounds__(256, 2) void gemm_bt(
    const short* __restrict__ A, const short* __restrict__ Bm,
    const float* __restrict__ bias, int K,
    short* __restrict__ qo, short* __restrict__ ko, short* __restrict__ vto,
    float* __restrict__ outf) {
  __shared__ __align__(16) char smem[16384];
  char* As = smem;
  char* Bs = smem + 8192;
  const int tid = threadIdx.x, lane = tid & 63, w = tid >> 6;
  const int wm = w >> 1, wn = w & 1;
  const int bm = blockIdx.y, bn = blockIdx.x;

  f32x4 acc[4][4];
  const f32x4 z4 = {0.f, 0.f, 0.f, 0.f};
#pragma unroll
  for (int m = 0; m < 4; ++m)
#pragma unroll
    for (int n = 0; n < 4; ++n) acc[m][n] = z4;

  const short* Abase = A + (size_t)bm * 128 * K;
  const short* Bbase = Bm + (size_t)bn * 128 * K;

  for (int k0 = 0; k0 < K; k0 += 32) {
    // stage: 8 calls for As, 8 for Bs; wave w does ia = 2w, 2w+1 of each
#pragma unroll
    for (int j = 0; j < 2; ++j) {
      int ia = w * 2 + j;
      int row = ia * 16 + (lane >> 2);
      int cl = (lane & 3) ^ (row & 3);   // logical K-chunk for this phys slot
      gload_lds16(Abase + (size_t)row * K + k0 + cl * 8, As + ia * 1024);
      gload_lds16(Bbase + (size_t)row * K + k0 + cl * 8, Bs + ia * 1024);
    }
    __syncthreads();

    bf16x8 af[4], bf[4];
#pragma unroll
    for (int m = 0; m < 4; ++m) {
      int r = wm * 64 + m * 16 + (lane & 15);
      af[m] = *(const bf16x8*)(As + r * 64 + ((((lane >> 4)) ^ (r & 3)) << 4));
    }
#pragma unroll
    for (int n = 0; n < 4; ++n) {
      int r = wn * 64 + n * 16 + (lane & 15);
      bf[n] = *(const bf16x8*)(Bs + r * 64 + ((((lane >> 4)) ^ (r & 3)) << 4));
    }
#pragma unroll
    for (int m = 0; m < 4; ++m)
#pragma unroll
      for (int n = 0; n < 4; ++n)
        acc[m][n] = __builtin_amdgcn_mfma_f32_16x16x32_bf16(af[m], bf[n], acc[m][n], 0, 0, 0);
    __syncthreads();
  }

  if (EPI == 0) {
    // cols: gn = bn*128 + wn*64 + nf*16 + (lane&15); which/head uniform per (block,wave)
    const int which = bn >> 3;               // 0=q 1=k 2=v
    const int hh = ((bn & 7) << 1) | wn;     // head
    const int bidx = bm >> 4;                // batch
    const size_t bh = (size_t)bidx * 16 + hh;
#pragma unroll
    for (int nf = 0; nf < 4; ++nf) {
      int dd = nf * 16 + (lane & 15);
      float bv = bias[bn * 128 + wn * 64 + dd];
#pragma unroll
      for (int m = 0; m < 4; ++m) {
        int nr0 = (bm & 15) * 128 + wm * 64 + m * 16 + ((lane >> 4) << 2);
        if (which == 2) {
          s16x4 pk;
#pragma unroll
          for (int r = 0; r < 4; ++r) pk[r] = f2bf(acc[m][nf][r] + bv);
          *(s16x4*)(vto + (bh * 64 + dd) * 2048 + nr0) = pk;
        } else if (which == 0) {
          short* dst = qo + (bh * 2048 + nr0) * 64 + dd;
#pragma unroll
          for (int r = 0; r < 4; ++r) dst[(size_t)r * 64] = f2bf((acc[m][nf][r] + bv) * 0.125f);
        } else {
          short* dst = ko + (bh * 2048 + nr0) * 64 + dd;
#pragma unroll
          for (int r = 0; r < 4; ++r) dst[(size_t)r * 64] = f2bf(acc[m][nf][r] + bv);
        }
      }
    }
  } else {
#pragma unroll
    for (int nf = 0; nf < 4; ++nf) {
      int gn = bn * 128 + wn * 64 + nf * 16 + (lane & 15);
      float bv = bias[gn];
#pragma unroll
      for (int m = 0; m < 4; ++m) {
        int gm0 = bm * 128 + wm * 64 + m * 16 + ((lane >> 4) << 2);
        float* dst = outf + (size_t)gm0 * 1024 + gn;
#pragma unroll
        for (int r = 0; r < 4; ++r) dst[(size_t)r * 1024] = acc[m][nf][r] + bv;
      }
    }
  }
}

// ---------------- flash attention ----------------
// grid (16 q-tiles, 64 bh). 4 waves; each wave owns 32 q rows.
// K LDS [128][64] swizzled; Vt LDS [64][128] swizzled; P per-wave [32][128] swizzled.
__global__ __launch_bounds__(256, 2) void attn_kernel(
    const short* __restrict__ q, const short* __restrict__ kk,
    const short* __restrict__ vt, short* __restrict__ ao) {
  __shared__ __align__(16) char smem[65536];
  char* Ks = smem;              // 16 KB
  char* Vs = smem + 16384;      // 16 KB
  const int tid = threadIdx.x, lane = tid & 63, w = tid >> 6;
  char* Ps = smem + 32768 + w * 8192;  // 8 KB per wave

  const int bh = blockIdx.y;
  const int qt = blockIdx.x;
  const short* qptr = q + (size_t)bh * 2048 * 64;
  const short* kptr = kk + (size_t)bh * 2048 * 64;
  const short* vptr = vt + (size_t)bh * 64 * 2048;

  // Q fragments in registers (already scaled by 1/8 at QKV epilogue)
  bf16x8 qf[2][2];
  const int qrow0 = qt * 128 + w * 32;
#pragma unroll
  for (int m = 0; m < 2; ++m)
#pragma unroll
    for (int kf = 0; kf < 2; ++kf)
      qf[m][kf] = *(const bf16x8*)(qptr + (size_t)(qrow0 + m * 16 + (lane & 15)) * 64 +
                                   (lane >> 4) * 8 + kf * 32);

  float mrun[2][4], lrun[2][4];
  f32x4 o[2][4];
  const f32x4 z4 = {0.f, 0.f, 0.f, 0.f};
#pragma unroll
  for (int m = 0; m < 2; ++m) {
#pragma unroll
    for (int r = 0; r < 4; ++r) { mrun[m][r] = -1e30f; lrun[m][r] = 0.f; }
#pragma unroll
    for (int nh = 0; nh < 4; ++nh) o[m][nh] = z4;
  }

  for (int t = 0; t < 2048; t += 128) {
    // stage K tile [128][64] (swizzled rows of 128B)
#pragma unroll
    for (int i = 0; i < 4; ++i) {
      int c = i * 256 + tid;
      int r = c >> 3, cc = (c & 7) * 8;
      uint4 dv = *(const uint4*)(kptr + (size_t)(t + r) * 64 + cc);
      *(uint4*)(Ks + r * 128 + ((cc * 2) ^ ((r & 7) << 4))) = dv;
    }
    // stage Vt tile [64][128] (swizzled rows of 256B)
#pragma unroll
    for (int i = 0; i < 4; ++i) {
      int c = i * 256 + tid;
      int r = c >> 4, cc = (c & 15) * 8;
      uint4 dv = *(const uint4*)(vptr + (size_t)r * 2048 + t + cc);
      *(uint4*)(Vs + r * 256 + ((cc * 2) ^ ((r & 7) << 4))) = dv;
    }
    __syncthreads();

    // S = Q K^T  (scale pre-folded into Q)
    f32x4 s[2][8];
#pragma unroll
    for (int m = 0; m < 2; ++m)
#pragma unroll
      for (int nf = 0; nf < 8; ++nf) s[m][nf] = z4;
#pragma unroll
    for (int kf = 0; kf < 2; ++kf) {
#pragma unroll
      for (int nf = 0; nf < 8; ++nf) {
        int r = nf * 16 + (lane & 15);
        int kb = (lane >> 4) * 16 + kf * 64;
        bf16x8 kfrag = *(const bf16x8*)(Ks + r * 128 + (kb ^ ((r & 7) << 4)));
#pragma unroll
        for (int m = 0; m < 2; ++m)
          s[m][nf] = __builtin_amdgcn_mfma_f32_16x16x32_bf16(qf[m][kf], kfrag, s[m][nf], 0, 0, 0);
      }
    }

    // online softmax; rows live in 16-lane groups (C layout: row=(lane>>4)*4+reg)
#pragma unroll
    for (int m = 0; m < 2; ++m) {
#pragma unroll
      for (int r = 0; r < 4; ++r) {
        float tm = -1e30f;
#pragma unroll
        for (int nf = 0; nf < 8; ++nf) tm = fmaxf(tm, s[m][nf][r]);
        tm = rmax16(tm);
        float mo = mrun[m][r];
        float mn = fmaxf(mo, tm);
        float scl = __expf(mo - mn);
        float ts = 0.f;
#pragma unroll
        for (int nf = 0; nf < 8; ++nf) {
          float p = __expf(s[m][nf][r] - mn);
          s[m][nf][r] = p;
          ts += p;
        }
        ts = rsum16(ts);
        lrun[m][r] = lrun[m][r] * scl + ts;
        mrun[m][r] = mn;
#pragma unroll
        for (int nh = 0; nh < 4; ++nh) o[m][nh][r] *= scl;
      }
    }

    // P (C layout) -> per-wave LDS as bf16 (A-frag layout readback)
#pragma unroll
    for (int m = 0; m < 2; ++m)
#pragma unroll
      for (int nf = 0; nf < 8; ++nf)
#pragma unroll
        for (int r = 0; r < 4; ++r) {
          int row = m * 16 + ((lane >> 4) << 2) + r;
          int colb = (nf * 16 + (lane & 15)) * 2;
          *(short*)(Ps + row * 256 + (colb ^ ((row & 7) << 4))) = f2bf(s[m][nf][r]);
        }

    // O += P V   (per-wave LDS; DS ops are in-order within a wave)
#pragma unroll
    for (int kf = 0; kf < 4; ++kf) {
      int kb = (lane >> 4) * 16 + kf * 64;
      bf16x8 pa[2], vb[4];
#pragma unroll
      for (int m = 0; m < 2; ++m) {
        int r = m * 16 + (lane & 15);
        pa[m] = *(const bf16x8*)(Ps + r * 256 + (kb ^ ((r & 7) << 4)));
      }
#pragma unroll
      for (int nh = 0; nh < 4; ++nh) {
        int r = nh * 16 + (lane & 15);
        vb[nh] = *(const bf16x8*)(Vs + r * 256 + (kb ^ ((r & 7) << 4)));
      }
#pragma unroll
      for (int m = 0; m < 2; ++m)
#pragma unroll
        for (int nh = 0; nh < 4; ++nh)
          o[m][nh] = __builtin_amdgcn_mfma_f32_16x16x32_bf16(pa[m], vb[nh], o[m][nh], 0, 0, 0);
    }
    __syncthreads();
  }

  // epilogue: O/l -> attn_out bf16 [B, N, D]
  const int b = bh >> 4, h = bh & 15;
#pragma unroll
  for (int m = 0; m < 2; ++m) {
#pragma unroll
    for (int r = 0; r < 4; ++r) {
      float inv = 1.f / lrun[m][r];
      int row = qrow0 + m * 16 + ((lane >> 4) << 2) + r;
#pragma unroll
      for (int nh = 0; nh < 4; ++nh) {
        int col = h * 64 + nh * 16 + (lane & 15);
        ao[((size_t)b * 2048 + row) * 1024 + col] = f2bf(o[m][nh][r] * inv);
      }
    }
  }
}

// ---------------- launch ----------------
extern "C" void kernel_launch(void* const* d_in, const int* in_sizes, int n_in,
                              void* d_out, int out_size, void* d_ws, size_t ws_size,
                              hipStream_t stream) {
  const float* x = (const float*)d_in[0];
  const float* qkv_w = (const float*)d_in[1];
  const float* qkv_b = (const float*)d_in[2];
  const float* proj_w = (const float*)d_in[3];
  const float* proj_b = (const float*)d_in[4];
  float* out = (float*)d_out;

  char* ws = (char*)d_ws;
  short* xb    = (short*)(ws + 0);          // 16 MB  [8192][1024]
  short* wqkv  = (short*)(ws + 16777216);   // 6 MB   [3072][1024]
  short* wproj = (short*)(ws + 23068672);   // 2 MB   [1024][1024]
  short* qb    = (short*)(ws + 25165824);   // 16 MB  [B,H,N,Hd]
  short* kb    = (short*)(ws + 41943040);   // 16 MB  [B,H,N,Hd]
  short* vtb   = (short*)(ws + 58720256);   // 16 MB  [B,H,Hd,N]
  short* aob   = (short*)(ws + 75497472);   // 16 MB  [B,N,D]
  // total 92,274,688 bytes

  cvt_f32_bf16<<<8192, 256, 0, stream>>>(x, xb, 2097152);
  cvt_f32_bf16<<<3072, 256, 0, stream>>>(qkv_w, wqkv, 786432);
  cvt_f32_bf16<<<1024, 256, 0, stream>>>(proj_w, wproj, 262144);

  gemm_bt<0><<<dim3(24, 64), 256, 0, stream>>>(xb, wqkv, qkv_b, 1024, qb, kb, vtb, nullptr);
  attn_kernel<<<dim3(16, 64), 256, 0, stream>>>(qb, kb, vtb, aob);
  gemm_bt<1><<<dim3(8, 64), 256, 0, stream>>>(aob, wproj, proj_b, 1024, nullptr, nullptr, nullptr, out);
}